// Round 1
// 356.708 us; speedup vs baseline: 1.0559x; 1.0559x over previous
//
#include <hip/hip_runtime.h>

typedef __attribute__((ext_vector_type(8))) short s16x8;
typedef __attribute__((ext_vector_type(4))) float f32x4;
typedef __attribute__((ext_vector_type(8))) unsigned short u16x8;

#define GLB(p) ((const __attribute__((address_space(1))) void*)(p))
#define LDS(p) ((__attribute__((address_space(3))) void*)(p))

#define BAR() __builtin_amdgcn_s_barrier()
#define LGKM(n) asm volatile("s_waitcnt lgkmcnt(" #n ")" ::: "memory")
#define VMC(n) asm volatile("s_waitcnt vmcnt(" #n ")" ::: "memory")

__device__ __forceinline__ unsigned short f2bf(float f) {
  unsigned u = __float_as_uint(f);
  u += 0x7fffu + ((u >> 16) & 1u);   // round-to-nearest-even on bf16 boundary
  return (unsigned short)(u >> 16);
}

// ---------------------------------------------------------------------------
// Kernel 1 (merged): blocks [0,2048) do per-row top-k masking of W;
// blocks [2048, 2048+16384) convert x fp32->bf16. (unchanged)
// ---------------------------------------------------------------------------
__global__ __launch_bounds__(256) void prep_kernel(
    const float* __restrict__ W, unsigned short* __restrict__ Wb,
    const float* __restrict__ X, unsigned short* __restrict__ Xb) {
  __shared__ int hist[4096];
  __shared__ int scanres[2];
  __shared__ int wsum[4];
  const int tid  = threadIdx.x;

  if (blockIdx.x >= 2048) {
    // ---- convert path ----
    const size_t i = ((size_t)(blockIdx.x - 2048) * 256 + tid) * 8;
    const float4* xp = (const float4*)(X + i);
    const float4 a = xp[0], b = xp[1];
    u16x8 o;
    o[0] = f2bf(a.x); o[1] = f2bf(a.y); o[2] = f2bf(a.z); o[3] = f2bf(a.w);
    o[4] = f2bf(b.x); o[5] = f2bf(b.y); o[6] = f2bf(b.z); o[7] = f2bf(b.w);
    *(u16x8*)(Xb + i) = o;
    return;
  }

  // ---- top-k path: exact k=1024 of 2048 by |w|, lowest-index tie-break ----
  const int lane = tid & 63;
  const int wv   = tid >> 6;
  const int row  = blockIdx.x;
  const float* wr = W + (size_t)row * 2048;

  const float4 v0 = *(const float4*)(wr + tid * 8);
  const float4 v1 = *(const float4*)(wr + tid * 8 + 4);
  float val[8] = {v0.x, v0.y, v0.z, v0.w, v1.x, v1.y, v1.z, v1.w};
  unsigned key[8];
#pragma unroll
  for (int e = 0; e < 8; ++e) key[e] = __float_as_uint(val[e]) & 0x7fffffffu;

  unsigned prefix = 0;
  int rem = 1024;

  // Round 0: bits [31:20], 4096 bins
  for (int i = tid; i < 4096; i += 256) hist[i] = 0;
  __syncthreads();
#pragma unroll
  for (int e = 0; e < 8; ++e) atomicAdd(&hist[key[e] >> 20], 1);
  __syncthreads();
  if (wv == 0) {
    const int base = 4096 - (lane + 1) * 64;
    int s = 0;
    for (int b = 0; b < 64; ++b) s += hist[base + b];
    int cum = s;
#pragma unroll
    for (int off = 1; off < 64; off <<= 1) {
      int o = __shfl_up(cum, off, 64);
      if (lane >= off) cum += o;
    }
    const int cumex = cum - s;
    if (cumex < rem && rem <= cum) {
      int running = cumex;
      for (int b = 63; b >= 0; --b) {
        int h = hist[base + b];
        if (running + h >= rem) { scanres[0] = base + b; scanres[1] = rem - running; break; }
        running += h;
      }
    }
  }
  __syncthreads();
  prefix = ((unsigned)scanres[0]) << 20;
  rem = scanres[1];
  __syncthreads();

  // Round 1: bits [19:10], 1024 bins
  for (int i = tid; i < 1024; i += 256) hist[i] = 0;
  __syncthreads();
#pragma unroll
  for (int e = 0; e < 8; ++e)
    if ((key[e] >> 20) == (prefix >> 20)) atomicAdd(&hist[(key[e] >> 10) & 1023], 1);
  __syncthreads();
  if (wv == 0) {
    const int base = 1024 - (lane + 1) * 16;
    int s = 0;
    for (int b = 0; b < 16; ++b) s += hist[base + b];
    int cum = s;
#pragma unroll
    for (int off = 1; off < 64; off <<= 1) {
      int o = __shfl_up(cum, off, 64);
      if (lane >= off) cum += o;
    }
    const int cumex = cum - s;
    if (cumex < rem && rem <= cum) {
      int running = cumex;
      for (int b = 15; b >= 0; --b) {
        int h = hist[base + b];
        if (running + h >= rem) { scanres[0] = base + b; scanres[1] = rem - running; break; }
        running += h;
      }
    }
  }
  __syncthreads();
  prefix |= ((unsigned)scanres[0]) << 10;
  rem = scanres[1];
  __syncthreads();

  // Round 2: bits [9:0], 1024 bins
  for (int i = tid; i < 1024; i += 256) hist[i] = 0;
  __syncthreads();
#pragma unroll
  for (int e = 0; e < 8; ++e)
    if ((key[e] >> 10) == (prefix >> 10)) atomicAdd(&hist[key[e] & 1023], 1);
  __syncthreads();
  if (wv == 0) {
    const int base = 1024 - (lane + 1) * 16;
    int s = 0;
    for (int b = 0; b < 16; ++b) s += hist[base + b];
    int cum = s;
#pragma unroll
    for (int off = 1; off < 64; off <<= 1) {
      int o = __shfl_up(cum, off, 64);
      if (lane >= off) cum += o;
    }
    const int cumex = cum - s;
    if (cumex < rem && rem <= cum) {
      int running = cumex;
      for (int b = 15; b >= 0; --b) {
        int h = hist[base + b];
        if (running + h >= rem) { scanres[0] = base + b; scanres[1] = rem - running; break; }
        running += h;
      }
    }
  }
  __syncthreads();
  const unsigned T = prefix | (unsigned)scanres[0];
  rem = scanres[1];

  // Tie resolution: block-ordered exclusive scan of ==T counts
  int eqcnt = 0;
#pragma unroll
  for (int e = 0; e < 8; ++e) eqcnt += (key[e] == T) ? 1 : 0;
  int c = eqcnt;
#pragma unroll
  for (int off = 1; off < 64; off <<= 1) {
    int o = __shfl_up(c, off, 64);
    if (lane >= off) c += o;
  }
  if (lane == 63) wsum[wv] = c;
  __syncthreads();
  int wavebase = 0;
  for (int j = 0; j < wv; ++j) wavebase += wsum[j];
  const int myex = wavebase + c - eqcnt;

  u16x8 o;
  int r = 0;
#pragma unroll
  for (int e = 0; e < 8; ++e) {
    const bool iseq = (key[e] == T);
    const bool keep = (key[e] > T) || (iseq && (myex + r) < rem);
    r += iseq ? 1 : 0;
    o[e] = keep ? f2bf(val[e]) : (unsigned short)0;
  }
  *(u16x8*)(Wb + (size_t)row * 2048 + tid * 8) = o;
}

// ---------------------------------------------------------------------------
// Kernel 2: bf16 GEMM, C = A(MxK) * B(NxK)^T + bias, fp32 out.
// 256x256 tile, BK=64, 8 waves (2M x 4N), 8-phase schedule with counted
// vmcnt (T3+T4), st_16x32 LDS XOR swizzle (T2), setprio around MFMA (T5).
//
// LDS (128 KiB): A: [0,64K) = 2 bufs x 256rows x 64cols bf16;
//                B: [64K,128K) same. Layout in 16x32 subtiles:
//   off(r,c) = (r>>4)<<11 | (c>>5)<<10 | (r&15)<<6 | (c&31)<<1
//   phys = off ^ (((off>>9)&1)<<5)            [XOR bit5 with bit9 = r&8]
// Staging writes linearly (global_load_lds dest = base + lane*16) with the
// INVERSE swizzle folded into each lane's global source coords; ds_reads
// apply the same XOR -> both-sides-or-neither (rule 21).
//
// Fragment-interleaved mapping: wave wm owns M 16-blocks {2i+wm}, wave wn
// owns N 16-blocks {4j+wn}. Hence phase (Mlo,Nlo) consumes exactly A-half0
// + B-half0, etc. Each phase restages the half-tile that died one barrier
// earlier:  ph1->(t+1).Bh0[buf^1], ph2->(t+2).Ah0, ph3->(t+2).Bh1,
// ph4->(t+2).Ah1 (all into this buf, whose halves are dead by then).
// vmcnt(6) once per K-tile (at ph4) => tile t+1 fully landed, 3 half-tiles
// stay in flight across barriers. vmcnt(0) only when prefetch stops (tail).
// ---------------------------------------------------------------------------
__global__ __launch_bounds__(512, 2) void gemm_bt_kernel(
    const unsigned short* __restrict__ A,   // M x K bf16
    const unsigned short* __restrict__ B,   // N x K bf16
    const float* __restrict__ bias,         // N
    float* __restrict__ C) {                // M x N fp32
  constexpr int K = 2048;
  constexpr int N = 2048;
  constexpr int T = K / 64;                 // 32 K-tiles
  constexpr size_t HK = (size_t)128 * K;    // half-tile row stride in elements

  __shared__ __align__(16) char lds_[131072];

  const int tid = threadIdx.x;
  const int l   = tid & 63;
  const int wv  = tid >> 6;
  const int wm  = wv & 1;                   // 2 M-waves
  const int wn  = wv >> 1;                  // 4 N-waves

  // XCD chunk swizzle: 512 blocks, 8 XCDs, 64 contiguous tiles each (bijective)
  const int lin = blockIdx.x;
  const int o   = (lin & 7) * 64 + (lin >> 3);
  const int tm  = o >> 3;                   // 64 M-tiles
  const int tn  = o & 7;                    // 8  N-tiles

  // staging source coords: dest byte d (linear) -> logical (r,c) via inverse
  // swizzle (involution): off = d ^ (((d>>9)&1)<<5)
  int rS[2], cS[2];
#pragma unroll
  for (int e = 0; e < 2; ++e) {
    const int d   = (e * 512 + tid) * 16;
    const int off = d ^ (((d >> 9) & 1) << 5);
    rS[e] = ((off >> 11) << 4) | ((off >> 6) & 15);
    cS[e] = (((off >> 10) & 1) << 5) | (((off >> 4) & 3) << 3);
  }
  const unsigned short* const pA0 = A + (size_t)(tm * 256 + rS[0]) * K + cS[0];
  const unsigned short* const pA1 = A + (size_t)(tm * 256 + rS[1]) * K + cS[1];
  const unsigned short* const pB0 = B + (size_t)(tn * 256 + rS[0]) * K + cS[0];
  const unsigned short* const pB1 = B + (size_t)(tn * 256 + rS[1]) * K + cS[1];

  // issue one half-tile (2 x global_load_lds dwordx4 per thread)
  auto stage = [&](const unsigned short* g0, const unsigned short* g1, char* d) {
    __builtin_amdgcn_global_load_lds(GLB(g0), LDS(d + wv * 1024), 16, 0, 0);
    __builtin_amdgcn_global_load_lds(GLB(g1), LDS(d + 8192 + wv * 1024), 16, 0, 0);
  };

  // swizzled per-lane ds_read offset: logical (row=l&15, col=(l>>4)*8),
  // XOR bit5 when row&8  -> 4-wide bank spread, ~conflict-free b128 reads
  const int laneoff = (((l & 15) << 6) | ((l >> 4) << 4)) ^ ((l & 8) << 2);
  const char* const aRd = (const char*)lds_ + wm * 2048 + laneoff;
  const char* const bRd = (const char*)lds_ + 65536 + wn * 2048 + laneoff;

  f32x4 acc[8][4] = {};

  // ---- prologue: tile0 all 4 halves, then tile1 {Ah0,Bh1,Ah1} (7 halves) ----
  stage(pA0,            pA1,            lds_);                          // (0,Ah0)
  stage(pB0 + HK,       pB1 + HK,       lds_ + 65536 + 16384);          // (0,Bh1)
  stage(pA0 + HK,       pA1 + HK,       lds_ + 16384);                  // (0,Ah1)
  stage(pB0,            pB1,            lds_ + 65536);                  // (0,Bh0)
  stage(pA0 + 64,       pA1 + 64,       lds_ + 32768);                  // (1,Ah0)
  stage(pB0 + HK + 64,  pB1 + HK + 64,  lds_ + 65536 + 32768 + 16384);  // (1,Bh1)
  stage(pA0 + HK + 64,  pA1 + HK + 64,  lds_ + 32768 + 16384);          // (1,Ah1)
  VMC(6);                               // first 8 loads (= tile0) landed
  BAR();

  for (int t = 0; t < T; ++t) {
    const int bb = t & 1;
    const char* aT = aRd + bb * 32768;
    const char* bT = bRd + bb * 32768;
    char* sA  = lds_ + bb * 32768;
    char* sB  = lds_ + 65536 + bb * 32768;
    char* sBn = lds_ + 65536 + (bb ^ 1) * 32768;

    s16x8 af[4][2], f0[2][2], f1[2][2];

    // ================= phase 1: (M-lo, N-lo) =================
#pragma unroll
    for (int i = 0; i < 4; ++i) {
      af[i][0] = *(const s16x8*)(aT + i * 4096);
      af[i][1] = *(const s16x8*)(aT + i * 4096 + 1024);
    }
#pragma unroll
    for (int j = 0; j < 2; ++j) {
      f0[j][0] = *(const s16x8*)(bT + j * 8192);
      f0[j][1] = *(const s16x8*)(bT + j * 8192 + 1024);
    }
    if (t + 1 < T)                                       // (t+1).Bh0 -> buf^1
      stage(pB0 + (size_t)(t + 1) * 64, pB1 + (size_t)(t + 1) * 64, sBn);
    LGKM(8);
    BAR();
    LGKM(0);
    __builtin_amdgcn_s_setprio(1);
#pragma unroll
    for (int kk = 0; kk < 2; ++kk)
#pragma unroll
      for (int i = 0; i < 4; ++i)
#pragma unroll
        for (int j = 0; j < 2; ++j)
          acc[i][j] = __builtin_amdgcn_mfma_f32_16x16x32_bf16(af[i][kk], f0[j][kk], acc[i][j], 0, 0, 0);
    __builtin_amdgcn_s_setprio(0);
    BAR();

    // ================= phase 2: (M-lo, N-hi) =================
#pragma unroll
    for (int j = 0; j < 2; ++j) {
      f1[j][0] = *(const s16x8*)(bT + 16384 + j * 8192);
      f1[j][1] = *(const s16x8*)(bT + 16384 + j * 8192 + 1024);
    }
    if (t + 2 < T)                                       // (t+2).Ah0 -> this buf
      stage(pA0 + (size_t)(t + 2) * 64, pA1 + (size_t)(t + 2) * 64, sA);
    BAR();
    LGKM(0);
    __builtin_amdgcn_s_setprio(1);
#pragma unroll
    for (int kk = 0; kk < 2; ++kk)
#pragma unroll
      for (int i = 0; i < 4; ++i)
#pragma unroll
        for (int j = 0; j < 2; ++j)
          acc[i][j + 2] = __builtin_amdgcn_mfma_f32_16x16x32_bf16(af[i][kk], f1[j][kk], acc[i][j + 2], 0, 0, 0);
    __builtin_amdgcn_s_setprio(0);
    BAR();

    // ================= phase 3: (M-hi, N-hi) =================
#pragma unroll
    for (int i = 0; i < 4; ++i) {
      af[i][0] = *(const s16x8*)(aT + 16384 + i * 4096);
      af[i][1] = *(const s16x8*)(aT + 16384 + i * 4096 + 1024);
    }
    if (t + 2 < T)                                       // (t+2).Bh1 -> this buf
      stage(pB0 + HK + (size_t)(t + 2) * 64, pB1 + HK + (size_t)(t + 2) * 64, sB + 16384);
    BAR();
    LGKM(0);
    __builtin_amdgcn_s_setprio(1);
#pragma unroll
    for (int kk = 0; kk < 2; ++kk)
#pragma unroll
      for (int i = 0; i < 4; ++i)
#pragma unroll
        for (int j = 0; j < 2; ++j)
          acc[i + 4][j + 2] = __builtin_amdgcn_mfma_f32_16x16x32_bf16(af[i][kk], f1[j][kk], acc[i + 4][j + 2], 0, 0, 0);
    __builtin_amdgcn_s_setprio(0);
    BAR();

    // ================= phase 4: (M-hi, N-lo) =================
#pragma unroll
    for (int j = 0; j < 2; ++j) {
      f0[j][0] = *(const s16x8*)(bT + j * 8192);
      f0[j][1] = *(const s16x8*)(bT + j * 8192 + 1024);
    }
    if (t + 2 < T)                                       // (t+2).Ah1 -> this buf
      stage(pA0 + HK + (size_t)(t + 2) * 64, pA1 + HK + (size_t)(t + 2) * 64, sA + 16384);
    BAR();
    LGKM(0);
    __builtin_amdgcn_s_setprio(1);
#pragma unroll
    for (int kk = 0; kk < 2; ++kk)
#pragma unroll
      for (int i = 0; i < 4; ++i)
#pragma unroll
        for (int j = 0; j < 2; ++j)
          acc[i + 4][j] = __builtin_amdgcn_mfma_f32_16x16x32_bf16(af[i][kk], f0[j][kk], acc[i + 4][j], 0, 0, 0);
    __builtin_amdgcn_s_setprio(0);
    if (t + 2 < T) { VMC(6); } else { VMC(0); }          // counted wait; drain only at tail
    BAR();
  }

  // ---- epilogue: C/D layout col = lane&15, row = (lane>>4)*4 + reg ----
  float bv[4];
#pragma unroll
  for (int j = 0; j < 4; ++j)
    bv[j] = bias[tn * 256 + (4 * j + wn) * 16 + (l & 15)];

  const int crow0 = tm * 256 + wm * 16 + (l >> 4) * 4;   // + i*32 + r
  const int ccol0 = tn * 256 + wn * 16 + (l & 15);       // + j*64
  float* Cp = C + (size_t)crow0 * N + ccol0;
#pragma unroll
  for (int i = 0; i < 8; ++i)
#pragma unroll
    for (int j = 0; j < 4; ++j)
#pragma unroll
      for (int r = 0; r < 4; ++r)
        Cp[(size_t)(i * 32 + r) * N + j * 64] = acc[i][j][r] + bv[j];
}

extern "C" void kernel_launch(void* const* d_in, const int* in_sizes, int n_in,
                              void* d_out, int out_size, void* d_ws, size_t ws_size,
                              hipStream_t stream) {
  const float* x    = (const float*)d_in[0];   // [8,2048,2048]
  const float* w    = (const float*)d_in[1];   // [2048,2048]
  const float* bias = (const float*)d_in[2];   // [2048]
  float* out = (float*)d_out;                  // [8,2048,2048]

  constexpr int M = 8 * 2048;
  constexpr int N = 2048;
  constexpr int K = 2048;

  unsigned short* xb = (unsigned short*)d_ws;        // M*K bf16 = 67.1 MB
  unsigned short* wb = xb + (size_t)M * K;           // N*K bf16 =  8.4 MB

  const int conv_blocks = ((size_t)M * K) / (256 * 8);
  prep_kernel<<<2048 + conv_blocks, 256, 0, stream>>>(w, wb, x, xb);
  gemm_bt_kernel<<<(M / 256) * (N / 256), 512, 0, stream>>>(xb, wb, bias, out);
}

// Round 2
// 351.405 us; speedup vs baseline: 1.0718x; 1.0151x over previous
//
#include <hip/hip_runtime.h>

typedef __attribute__((ext_vector_type(8))) short s16x8;
typedef __attribute__((ext_vector_type(4))) float f32x4;
typedef __attribute__((ext_vector_type(8))) unsigned short u16x8;

#define GLB(p) ((const __attribute__((address_space(1))) void*)(p))
#define LDS(p) ((__attribute__((address_space(3))) void*)(p))

#define BAR() __builtin_amdgcn_s_barrier()
#define VMC(n) asm volatile("s_waitcnt vmcnt(" #n ")" ::: "memory")

__device__ __forceinline__ unsigned short f2bf(float f) {
  unsigned u = __float_as_uint(f);
  u += 0x7fffu + ((u >> 16) & 1u);   // round-to-nearest-even on bf16 boundary
  return (unsigned short)(u >> 16);
}

// ---------------------------------------------------------------------------
// Kernel 1 (merged): blocks [0,2048) do per-row top-k masking of W;
// blocks [2048, 2048+16384) convert x fp32->bf16. (unchanged)
// ---------------------------------------------------------------------------
__global__ __launch_bounds__(256) void prep_kernel(
    const float* __restrict__ W, unsigned short* __restrict__ Wb,
    const float* __restrict__ X, unsigned short* __restrict__ Xb) {
  __shared__ int hist[4096];
  __shared__ int scanres[2];
  __shared__ int wsum[4];
  const int tid  = threadIdx.x;

  if (blockIdx.x >= 2048) {
    // ---- convert path ----
    const size_t i = ((size_t)(blockIdx.x - 2048) * 256 + tid) * 8;
    const float4* xp = (const float4*)(X + i);
    const float4 a = xp[0], b = xp[1];
    u16x8 o;
    o[0] = f2bf(a.x); o[1] = f2bf(a.y); o[2] = f2bf(a.z); o[3] = f2bf(a.w);
    o[4] = f2bf(b.x); o[5] = f2bf(b.y); o[6] = f2bf(b.z); o[7] = f2bf(b.w);
    *(u16x8*)(Xb + i) = o;
    return;
  }

  // ---- top-k path: exact k=1024 of 2048 by |w|, lowest-index tie-break ----
  const int lane = tid & 63;
  const int wv   = tid >> 6;
  const int row  = blockIdx.x;
  const float* wr = W + (size_t)row * 2048;

  const float4 v0 = *(const float4*)(wr + tid * 8);
  const float4 v1 = *(const float4*)(wr + tid * 8 + 4);
  float val[8] = {v0.x, v0.y, v0.z, v0.w, v1.x, v1.y, v1.z, v1.w};
  unsigned key[8];
#pragma unroll
  for (int e = 0; e < 8; ++e) key[e] = __float_as_uint(val[e]) & 0x7fffffffu;

  unsigned prefix = 0;
  int rem = 1024;

  // Round 0: bits [31:20], 4096 bins
  for (int i = tid; i < 4096; i += 256) hist[i] = 0;
  __syncthreads();
#pragma unroll
  for (int e = 0; e < 8; ++e) atomicAdd(&hist[key[e] >> 20], 1);
  __syncthreads();
  if (wv == 0) {
    const int base = 4096 - (lane + 1) * 64;
    int s = 0;
    for (int b = 0; b < 64; ++b) s += hist[base + b];
    int cum = s;
#pragma unroll
    for (int off = 1; off < 64; off <<= 1) {
      int o = __shfl_up(cum, off, 64);
      if (lane >= off) cum += o;
    }
    const int cumex = cum - s;
    if (cumex < rem && rem <= cum) {
      int running = cumex;
      for (int b = 63; b >= 0; --b) {
        int h = hist[base + b];
        if (running + h >= rem) { scanres[0] = base + b; scanres[1] = rem - running; break; }
        running += h;
      }
    }
  }
  __syncthreads();
  prefix = ((unsigned)scanres[0]) << 20;
  rem = scanres[1];
  __syncthreads();

  // Round 1: bits [19:10], 1024 bins
  for (int i = tid; i < 1024; i += 256) hist[i] = 0;
  __syncthreads();
#pragma unroll
  for (int e = 0; e < 8; ++e)
    if ((key[e] >> 20) == (prefix >> 20)) atomicAdd(&hist[(key[e] >> 10) & 1023], 1);
  __syncthreads();
  if (wv == 0) {
    const int base = 1024 - (lane + 1) * 16;
    int s = 0;
    for (int b = 0; b < 16; ++b) s += hist[base + b];
    int cum = s;
#pragma unroll
    for (int off = 1; off < 64; off <<= 1) {
      int o = __shfl_up(cum, off, 64);
      if (lane >= off) cum += o;
    }
    const int cumex = cum - s;
    if (cumex < rem && rem <= cum) {
      int running = cumex;
      for (int b = 15; b >= 0; --b) {
        int h = hist[base + b];
        if (running + h >= rem) { scanres[0] = base + b; scanres[1] = rem - running; break; }
        running += h;
      }
    }
  }
  __syncthreads();
  prefix |= ((unsigned)scanres[0]) << 10;
  rem = scanres[1];
  __syncthreads();

  // Round 2: bits [9:0], 1024 bins
  for (int i = tid; i < 1024; i += 256) hist[i] = 0;
  __syncthreads();
#pragma unroll
  for (int e = 0; e < 8; ++e)
    if ((key[e] >> 10) == (prefix >> 10)) atomicAdd(&hist[key[e] & 1023], 1);
  __syncthreads();
  if (wv == 0) {
    const int base = 1024 - (lane + 1) * 16;
    int s = 0;
    for (int b = 0; b < 16; ++b) s += hist[base + b];
    int cum = s;
#pragma unroll
    for (int off = 1; off < 64; off <<= 1) {
      int o = __shfl_up(cum, off, 64);
      if (lane >= off) cum += o;
    }
    const int cumex = cum - s;
    if (cumex < rem && rem <= cum) {
      int running = cumex;
      for (int b = 15; b >= 0; --b) {
        int h = hist[base + b];
        if (running + h >= rem) { scanres[0] = base + b; scanres[1] = rem - running; break; }
        running += h;
      }
    }
  }
  __syncthreads();
  const unsigned T = prefix | (unsigned)scanres[0];
  rem = scanres[1];

  // Tie resolution: block-ordered exclusive scan of ==T counts
  int eqcnt = 0;
#pragma unroll
  for (int e = 0; e < 8; ++e) eqcnt += (key[e] == T) ? 1 : 0;
  int c = eqcnt;
#pragma unroll
  for (int off = 1; off < 64; off <<= 1) {
    int o = __shfl_up(c, off, 64);
    if (lane >= off) c += o;
  }
  if (lane == 63) wsum[wv] = c;
  __syncthreads();
  int wavebase = 0;
  for (int j = 0; j < wv; ++j) wavebase += wsum[j];
  const int myex = wavebase + c - eqcnt;

  u16x8 o;
  int r = 0;
#pragma unroll
  for (int e = 0; e < 8; ++e) {
    const bool iseq = (key[e] == T);
    const bool keep = (key[e] > T) || (iseq && (myex + r) < rem);
    r += iseq ? 1 : 0;
    o[e] = keep ? f2bf(val[e]) : (unsigned short)0;
  }
  *(u16x8*)(Wb + (size_t)row * 2048 + tid * 8) = o;
}

// ---------------------------------------------------------------------------
// Kernel 2: bf16 GEMM, C = A(MxK) * B(NxK)^T + bias, fp32 out.
// 256x256 tile, BK=64, 8 waves (2M x 4N). Pipelined 4-phase schedule:
// ONE barrier per phase; each phase's fragments are (mostly) issued during
// the previous phase's MFMA window so the LDS pipe and MFMA pipe overlap.
//
//   ph1: stage Bh0(t+1)->buf^1 | read aLo(8,kk-ordered)+bLo(4)+bHi(4 pre)
//        | MFMA1 aLo x bLo  -> acc[0..3][0..1]                       | BAR
//   ph2: stage Ah0(t+2)       | MFMA2 aLo x bHi -> acc[0..3][2..3]
//        | read aHi(8) into af (af dead after MFMA2 issue)           | BAR
//   ph3: stage Bh1(t+2)       | MFMA3 aHi x bHi -> acc[4..7][2..3]
//        | re-read bLo(4) (dead since MFMA1)                         | BAR
//   ph4: stage Ah1(t+2)       | MFMA4 aHi x bLo -> acc[4..7][0..1]
//        | VMC(6) (counted; 3 half-tiles stay in flight)             | BAR
//
// WAR safety of each stage (1 barrier/phase): readers of the overwritten
// region complete before their own MFMA of the PREVIOUS phase, which
// precedes the barrier that precedes the stage issue. RAW: stage order per
// tile identical to before => VMC(6) at ph4 retires exactly tile t+1.
// No explicit lgkmcnt: fragment reads are plain loads, compiler emits
// precise counted waits (and explicit lgkm(0) would wrongly drain the
// prefetch reads).
// LDS swizzle (st_16x32 XOR) + XCD chunk swizzle unchanged from round 1.
// ---------------------------------------------------------------------------
__global__ __launch_bounds__(512, 2) void gemm_bt_kernel(
    const unsigned short* __restrict__ A,   // M x K bf16
    const unsigned short* __restrict__ B,   // N x K bf16
    const float* __restrict__ bias,         // N
    float* __restrict__ C) {                // M x N fp32
  constexpr int K = 2048;
  constexpr int N = 2048;
  constexpr int T = K / 64;                 // 32 K-tiles
  constexpr size_t HK = (size_t)128 * K;    // half-tile row stride in elements

  __shared__ __align__(16) char lds_[131072];

  const int tid = threadIdx.x;
  const int l   = tid & 63;
  const int wv  = tid >> 6;
  const int wm  = wv & 1;                   // 2 M-waves
  const int wn  = wv >> 1;                  // 4 N-waves

  // XCD chunk swizzle: 512 blocks, 8 XCDs, 64 contiguous tiles each (bijective)
  const int lin = blockIdx.x;
  const int o   = (lin & 7) * 64 + (lin >> 3);
  const int tm  = o >> 3;                   // 64 M-tiles
  const int tn  = o & 7;                    // 8  N-tiles

  // staging source coords: dest byte d (linear) -> logical (r,c) via inverse
  // swizzle (involution): off = d ^ (((d>>9)&1)<<5)
  int rS[2], cS[2];
#pragma unroll
  for (int e = 0; e < 2; ++e) {
    const int d   = (e * 512 + tid) * 16;
    const int off = d ^ (((d >> 9) & 1) << 5);
    rS[e] = ((off >> 11) << 4) | ((off >> 6) & 15);
    cS[e] = (((off >> 10) & 1) << 5) | (((off >> 4) & 3) << 3);
  }
  const unsigned short* const pA0 = A + (size_t)(tm * 256 + rS[0]) * K + cS[0];
  const unsigned short* const pA1 = A + (size_t)(tm * 256 + rS[1]) * K + cS[1];
  const unsigned short* const pB0 = B + (size_t)(tn * 256 + rS[0]) * K + cS[0];
  const unsigned short* const pB1 = B + (size_t)(tn * 256 + rS[1]) * K + cS[1];

  // issue one half-tile (2 x global_load_lds dwordx4 per thread)
  auto stage = [&](const unsigned short* g0, const unsigned short* g1, char* d) {
    __builtin_amdgcn_global_load_lds(GLB(g0), LDS(d + wv * 1024), 16, 0, 0);
    __builtin_amdgcn_global_load_lds(GLB(g1), LDS(d + 8192 + wv * 1024), 16, 0, 0);
  };

  // swizzled per-lane ds_read offset: logical (row=l&15, col=(l>>4)*8),
  // XOR bit5 when row&8  -> 4-wide bank spread, ~conflict-free b128 reads
  const int laneoff = (((l & 15) << 6) | ((l >> 4) << 4)) ^ ((l & 8) << 2);
  const char* const aRd = (const char*)lds_ + wm * 2048 + laneoff;
  const char* const bRd = (const char*)lds_ + 65536 + wn * 2048 + laneoff;

  f32x4 acc[8][4] = {};

  // ---- prologue: tile0 all 4 halves, then tile1 {Ah0,Bh1,Ah1} (7 halves) ----
  stage(pA0,            pA1,            lds_);                          // (0,Ah0)
  stage(pB0 + HK,       pB1 + HK,       lds_ + 65536 + 16384);          // (0,Bh1)
  stage(pA0 + HK,       pA1 + HK,       lds_ + 16384);                  // (0,Ah1)
  stage(pB0,            pB1,            lds_ + 65536);                  // (0,Bh0)
  stage(pA0 + 64,       pA1 + 64,       lds_ + 32768);                  // (1,Ah0)
  stage(pB0 + HK + 64,  pB1 + HK + 64,  lds_ + 65536 + 32768 + 16384);  // (1,Bh1)
  stage(pA0 + HK + 64,  pA1 + HK + 64,  lds_ + 32768 + 16384);          // (1,Ah1)
  VMC(6);                               // first 8 loads (= tile0) landed
  BAR();

  for (int t = 0; t < T; ++t) {
    const int bb = t & 1;
    const char* aT = aRd + bb * 32768;
    const char* bT = bRd + bb * 32768;
    char* sA  = lds_ + bb * 32768;
    char* sB  = lds_ + 65536 + bb * 32768;
    char* sBn = lds_ + 65536 + (bb ^ 1) * 32768;

    s16x8 af[4][2], bLo[2][2], bHi[2][2];

    // ================= phase 1: (M-lo, N-lo) =================
    if (t + 1 < T)                                       // (t+1).Bh0 -> buf^1
      stage(pB0 + (size_t)(t + 1) * 64, pB1 + (size_t)(t + 1) * 64, sBn);
    // reads, kk0 first so compiler can partial-wait; bHi is pure prefetch
#pragma unroll
    for (int i = 0; i < 4; ++i)
      af[i][0] = *(const s16x8*)(aT + i * 4096);
#pragma unroll
    for (int j = 0; j < 2; ++j)
      bLo[j][0] = *(const s16x8*)(bT + j * 8192);
#pragma unroll
    for (int i = 0; i < 4; ++i)
      af[i][1] = *(const s16x8*)(aT + i * 4096 + 1024);
#pragma unroll
    for (int j = 0; j < 2; ++j)
      bLo[j][1] = *(const s16x8*)(bT + j * 8192 + 1024);
#pragma unroll
    for (int j = 0; j < 2; ++j) {
      bHi[j][0] = *(const s16x8*)(bT + 16384 + j * 8192);
      bHi[j][1] = *(const s16x8*)(bT + 16384 + j * 8192 + 1024);
    }
    __builtin_amdgcn_s_setprio(1);
#pragma unroll
    for (int kk = 0; kk < 2; ++kk)
#pragma unroll
      for (int i = 0; i < 4; ++i)
#pragma unroll
        for (int j = 0; j < 2; ++j)
          acc[i][j] = __builtin_amdgcn_mfma_f32_16x16x32_bf16(af[i][kk], bLo[j][kk], acc[i][j], 0, 0, 0);
    __builtin_amdgcn_s_setprio(0);
    BAR();

    // ================= phase 2: (M-lo, N-hi) =================
    if (t + 2 < T)                                       // (t+2).Ah0 -> this buf
      stage(pA0 + (size_t)(t + 2) * 64, pA1 + (size_t)(t + 2) * 64, sA);
    __builtin_amdgcn_s_setprio(1);
#pragma unroll
    for (int kk = 0; kk < 2; ++kk)
#pragma unroll
      for (int i = 0; i < 4; ++i)
#pragma unroll
        for (int j = 0; j < 2; ++j)
          acc[i][j + 2] = __builtin_amdgcn_mfma_f32_16x16x32_bf16(af[i][kk], bHi[j][kk], acc[i][j + 2], 0, 0, 0);
    __builtin_amdgcn_s_setprio(0);
    // prefetch A-hi into af: af is dead once MFMA2 has issued (in-order issue;
    // HW/compiler handle the VGPR WAR distance)
#pragma unroll
    for (int i = 0; i < 4; ++i) {
      af[i][0] = *(const s16x8*)(aT + 16384 + i * 4096);
      af[i][1] = *(const s16x8*)(aT + 16384 + i * 4096 + 1024);
    }
    BAR();

    // ================= phase 3: (M-hi, N-hi) =================
    if (t + 2 < T)                                       // (t+2).Bh1 -> this buf
      stage(pB0 + HK + (size_t)(t + 2) * 64, pB1 + HK + (size_t)(t + 2) * 64, sB + 16384);
    __builtin_amdgcn_s_setprio(1);
#pragma unroll
    for (int kk = 0; kk < 2; ++kk)
#pragma unroll
      for (int i = 0; i < 4; ++i)
#pragma unroll
        for (int j = 0; j < 2; ++j)
          acc[i + 4][j + 2] = __builtin_amdgcn_mfma_f32_16x16x32_bf16(af[i][kk], bHi[j][kk], acc[i + 4][j + 2], 0, 0, 0);
    __builtin_amdgcn_s_setprio(0);
    // re-read bLo for phase 4 (dead since MFMA1)
#pragma unroll
    for (int j = 0; j < 2; ++j) {
      bLo[j][0] = *(const s16x8*)(bT + j * 8192);
      bLo[j][1] = *(const s16x8*)(bT + j * 8192 + 1024);
    }
    BAR();

    // ================= phase 4: (M-hi, N-lo) =================
    if (t + 2 < T)                                       // (t+2).Ah1 -> this buf
      stage(pA0 + HK + (size_t)(t + 2) * 64, pA1 + HK + (size_t)(t + 2) * 64, sA + 16384);
    __builtin_amdgcn_s_setprio(1);
#pragma unroll
    for (int kk = 0; kk < 2; ++kk)
#pragma unroll
      for (int i = 0; i < 4; ++i)
#pragma unroll
        for (int j = 0; j < 2; ++j)
          acc[i + 4][j] = __builtin_amdgcn_mfma_f32_16x16x32_bf16(af[i][kk], bLo[j][kk], acc[i + 4][j], 0, 0, 0);
    __builtin_amdgcn_s_setprio(0);
    if (t + 2 < T) { VMC(6); } else { VMC(0); }          // counted wait; drain only at tail
    BAR();
  }

  // ---- epilogue: C/D layout col = lane&15, row = (lane>>4)*4 + reg ----
  float bv[4];
#pragma unroll
  for (int j = 0; j < 4; ++j)
    bv[j] = bias[tn * 256 + (4 * j + wn) * 16 + (l & 15)];

  const int crow0 = tm * 256 + wm * 16 + (l >> 4) * 4;   // + i*32 + r
  const int ccol0 = tn * 256 + wn * 16 + (l & 15);       // + j*64
  float* Cp = C + (size_t)crow0 * N + ccol0;
#pragma unroll
  for (int i = 0; i < 8; ++i)
#pragma unroll
    for (int j = 0; j < 4; ++j)
#pragma unroll
      for (int r = 0; r < 4; ++r)
        Cp[(size_t)(i * 32 + r) * N + j * 64] = acc[i][j][r] + bv[j];
}

extern "C" void kernel_launch(void* const* d_in, const int* in_sizes, int n_in,
                              void* d_out, int out_size, void* d_ws, size_t ws_size,
                              hipStream_t stream) {
  const float* x    = (const float*)d_in[0];   // [8,2048,2048]
  const float* w    = (const float*)d_in[1];   // [2048,2048]
  const float* bias = (const float*)d_in[2];   // [2048]
  float* out = (float*)d_out;                  // [8,2048,2048]

  constexpr int M = 8 * 2048;
  constexpr int N = 2048;
  constexpr int K = 2048;

  unsigned short* xb = (unsigned short*)d_ws;        // M*K bf16 = 67.1 MB
  unsigned short* wb = xb + (size_t)M * K;           // N*K bf16 =  8.4 MB

  const int conv_blocks = ((size_t)M * K) / (256 * 8);
  prep_kernel<<<2048 + conv_blocks, 256, 0, stream>>>(w, wb, x, xb);
  gemm_bt_kernel<<<(M / 256) * (N / 256), 512, 0, stream>>>(xb, wb, bias, out);
}